// Round 6
// baseline (427.512 us; speedup 1.0000x reference)
//
#include <hip/hip_runtime.h>
#include <math.h>

#define EPS_F 1e-5f
#define NPOINTS 550   // sum_{i=1..10} 10*i
#define CIN 512

// jax.nn.softplus(z) = max(z,0) + log1p(exp(-|z|))
static __device__ __forceinline__ float softplus_f(float z) {
    return fmaxf(z, 0.0f) + log1pf(expf(-fabsf(z)));
}

// ================= Kernel A: chain-free partial dual-GEMV ==================
// 16 lanes per row; lane c accumulates cols [c*4 + 64*j] slices privately.
// Per wave-iteration: 8 dwordx4 loads -> 64 FMA -> one float2 store.
// NO shuffles, NO lds handoff, NO barriers in the loop -> loads pipeline
// freely across grid-stride iterations. grid 2048 x 256thr = 8 blocks/CU.
__global__ __launch_bounds__(256, 8) void gemv_part_kernel(
    const float* __restrict__ x,
    const float* __restrict__ Wa, const float* __restrict__ Wb,
    float2* __restrict__ part,           // [row*16 + c] = (pa, pb)
    int nRowGrp)                         // batch/4
{
    __shared__ float4 WaL[128], WbL[128];
    const int tid = threadIdx.x;
    if (tid < 128) {
        WaL[tid] = ((const float4*)Wa)[tid];
        WbL[tid] = ((const float4*)Wb)[tid];
    }
    __syncthreads();

    const int lane = tid & 63;
    const int wave = tid >> 6;
    const int r = lane >> 4;             // 0..3 row within group
    const int c = lane & 15;             // 16-lane column slice
    const int stride = gridDim.x * 4;

    for (int rg = blockIdx.x * 4 + wave; rg < nRowGrp; rg += stride) {
        const long row = (long)rg * 4 + r;
        const float4* xp = (const float4*)(x + row * CIN) + c;

        float4 xv[8];
        #pragma unroll
        for (int j = 0; j < 8; ++j)       // 8 loads back-to-back, imm offsets
            xv[j] = xp[16 * j];

        float pa = 0.0f, pb = 0.0f;
        #pragma unroll
        for (int j = 0; j < 8; ++j) {
            const float4 wa = WaL[16 * j + c];   // broadcast within 16-lane grp
            const float4 wb = WbL[16 * j + c];
            pa = fmaf(xv[j].x, wa.x, pa);
            pa = fmaf(xv[j].y, wa.y, pa);
            pa = fmaf(xv[j].z, wa.z, pa);
            pa = fmaf(xv[j].w, wa.w, pa);
            pb = fmaf(xv[j].x, wb.x, pb);
            pb = fmaf(xv[j].y, wb.y, pb);
            pb = fmaf(xv[j].z, wb.z, pb);
            pb = fmaf(xv[j].w, wb.w, pb);
        }
        part[row * 16 + c] = make_float2(pa, pb);  // 512 B contiguous / wave
    }
}

// ===================== Kernel B: reduce + quadrature =======================
// Thread-per-row: sum 16 partials (coalesced 128 B), then 550-point
// quadrature fully thread-local (broadcast LDS table, no cross-lane).
__global__ __launch_bounds__(256, 4) void quad_kernel(
    const float2* __restrict__ part,
    const float* __restrict__ ba, const float* __restrict__ bb,
    float* __restrict__ out)
{
    __shared__ __align__(16) float2 tab[NPOINTS];  // (log2 g, log2(1-g))
    __shared__ float outb[256 * 10];

    const int tid = threadIdx.x;

    for (int p = tid; p < NPOINTS; p += 256) {
        int i = 1, off = 0;
        while (p >= off + 10 * i) { off += 10 * i; ++i; }
        const int j = p - off;
        const int n = 10 * i;
        const float thr = (float)i * 0.1f;
        const float step = (thr - 2.0f * EPS_F) / (float)(n - 1);
        const float gx = EPS_F + step * (float)j;   // matches jnp.linspace f32
        float2 e;
        e.x = log2f(gx);
        e.y = log2f(1.0f - gx);
        tab[p] = e;
    }
    __syncthreads();

    const long row = (long)blockIdx.x * 256 + tid;
    const float4* pp = (const float4*)(part + row * 16);  // 8 x float4
    float da = 0.0f, db = 0.0f;
    #pragma unroll
    for (int j = 0; j < 8; ++j) {
        const float4 v = pp[j];          // (pa0, pb0, pa1, pb1)
        da += v.x + v.z;
        db += v.y + v.w;
    }

    const float za = da + ba[0];
    const float zb = db + bb[0];
    const float alpha = fminf(fmaxf(1.0f + softplus_f(za), 1.0f), 100.0f);
    const float beta  = fminf(fmaxf(1.0f + softplus_f(zb), 1.0f), 100.0f);
    const float am1 = alpha - 1.0f;
    const float bm1 = beta - 1.0f;

    // Stabilizer at the Beta mode (lbeta/dx are common positive factors and
    // cancel in the normalization; concave exponent => exp2 args <= 0).
    const float denom = am1 + bm1;
    float mode = (denom > 0.0f) ? (am1 / denom) : 0.5f;
    mode = fminf(fmaxf(mode, 1e-7f), 1.0f - 1.1920929e-7f);
    const float nM2 = -(am1 * log2f(mode) + bm1 * log2f(1.0f - mode));

    float seg[10];                       // per-threshold quadrature sums
    int p0 = 0;
    #pragma unroll
    for (int i = 1; i <= 10; ++i) {
        const int n = 10 * i;            // even; p0 even -> float4-aligned
        float s2 = 0.0f;
        for (int j = 0; j < n; j += 2) {
            const float4 tq = *(const float4*)&tab[p0 + j];  // broadcast read
            const float e0 = fmaf(am1, tq.x, fmaf(bm1, tq.y, nM2));
            const float e1 = fmaf(am1, tq.z, fmaf(bm1, tq.w, nM2));
            s2 += __builtin_amdgcn_exp2f(e0) + __builtin_amdgcn_exp2f(e1);
        }
        seg[i - 1] = s2;
        p0 += n;
    }

    const float inv = 1.0f / seg[9];
    float prev = 0.0f;
    #pragma unroll
    for (int kk = 0; kk < 10; ++kk) {
        outb[tid * 10 + kk] = (seg[kk] - prev) * inv;
        prev = seg[kk];
    }
    __syncthreads();

    // coalesced block write: 2560 floats = 640 float4
    const float4* s4 = (const float4*)outb;
    float4* dst = (float4*)(out + (size_t)blockIdx.x * 2560);
    #pragma unroll
    for (int idx = tid; idx < 640; idx += 256) dst[idx] = s4[idx];
}

extern "C" void kernel_launch(void* const* d_in, const int* in_sizes, int n_in,
                              void* d_out, int out_size, void* d_ws, size_t ws_size,
                              hipStream_t stream) {
    const float* x  = (const float*)d_in[0];
    const float* Wa = (const float*)d_in[1];
    const float* ba = (const float*)d_in[2];
    const float* Wb = (const float*)d_in[3];
    const float* bb = (const float*)d_in[4];
    float* out = (float*)d_out;
    float2* part = (float2*)d_ws;        // 16.8 MB: [batch][16] (pa,pb)

    const int batch = in_sizes[0] / CIN;          // 131072
    const int nRowGrp = batch / 4;                // 32768
    gemv_part_kernel<<<2048, 256, 0, stream>>>(x, Wa, Wb, part, nRowGrp);
    quad_kernel<<<batch / 256, 256, 0, stream>>>(part, ba, bb, out);
}